// Round 2
// baseline (455.014 us; speedup 1.0000x reference)
//
#include <hip/hip_runtime.h>

#define BB 4
#define NN 512
#define HH 128
#define EHH 128
#define JB 64
#define NCH (NN/JB)

typedef short short8 __attribute__((ext_vector_type(8)));
typedef float f32x4 __attribute__((ext_vector_type(4)));

__device__ __forceinline__ float fsilu(float x){
    float e = __expf(-x);
    return x * __builtin_amdgcn_rcpf(1.0f + e);
}

__device__ __forceinline__ unsigned int cvt_pk_bf16(float lo, float hi){
    unsigned int r;
    asm("v_cvt_pk_bf16_f32 %0, %1, %2" : "=v"(r) : "v"(lo), "v"(hi));
    return r;
}

__device__ __forceinline__ unsigned short f2bf(float f){
    return (unsigned short)(cvt_pk_bf16(f, 0.f) & 0xffffu);
}

__device__ __forceinline__ unsigned char f2fp8(float f){
#if __has_builtin(__builtin_amdgcn_cvt_pk_fp8_f32)
    int r = __builtin_amdgcn_cvt_pk_fp8_f32(f, 0.f, 0, false);
    return (unsigned char)(r & 0xff);
#else
    unsigned int u = __float_as_uint(f);
    unsigned int sign = (u >> 24) & 0x80;
    float a = fabsf(f);
    if (!(a > 0.f)) return (unsigned char)sign;
    if (a >= 448.f) return (unsigned char)(sign | 0x7E);
    int e = (int)((u >> 23) & 0xFF) - 127;
    if (e < -6){
        int m = (int)(a * 512.f + 0.5f);
        return (unsigned char)(sign | m);
    }
    unsigned int mant = (u >> 20) & 0x7;
    unsigned int rest = u & 0xFFFFF;
    unsigned int exp8 = (unsigned int)(e + 7);
    if (rest > 0x80000 || (rest == 0x80000 && (mant & 1))){
        mant++;
        if (mant == 8){ mant = 0; exp8++; }
    }
    if (exp8 >= 16) return (unsigned char)(sign | 0x7E);
    return (unsigned char)(sign | (exp8 << 3) | mant);
#endif
}

// ---------------- prep: projections + weight conversions ------------------
__global__ __launch_bounds__(128) void k_prep(
    const float* __restrict__ h,
    const float* __restrict__ We1, const float* __restrict__ be1,
    const float* __restrict__ We2, const float* __restrict__ Wc1,
    float* __restrict__ hi_e, unsigned short* __restrict__ hj_eb,
    unsigned short* __restrict__ We2T, unsigned char* __restrict__ Wc1F8)
{
    const int tid = threadIdx.x;
    if (blockIdx.x < BB*NN) {
        __shared__ float hrow[HH];
        const int row = blockIdx.x;
        hrow[tid] = h[row*HH + tid];
        __syncthreads();
        float a0 = be1[tid];   // fold be1 into hi_e
        float a1 = 0.f;
        #pragma unroll 8
        for (int k = 0; k < HH; ++k){
            float hv = hrow[k];
            a0 += hv * We1[k*EHH + tid];
            a1 += hv * We1[(HH + k)*EHH + tid];
        }
        hi_e[row*EHH + tid] = a0;
        hj_eb[row*EHH + tid] = f2bf(a1);
    } else {
        const int bid = blockIdx.x - BB*NN;   // 0..31
        for (int t = bid*128 + tid; t < 128*128; t += 32*128){
            int o = t >> 7, kk = t & 127;
            We2T[t] = f2bf(We2[kk*HH + o]);          // We2T[col][k]
        }
        for (int idx = bid*128 + tid; idx < 8192; idx += 32*128){
            int o = idx >> 6, kp = idx & 63;
            int k = 2*kp;
            float f0 = Wc1[k*EHH + o] * 16.f;
            float f1 = Wc1[(k+1)*EHH + o] * 16.f;
            unsigned short pk = (unsigned short)(f2fp8(f0) | ((unsigned short)f2fp8(f1) << 8));
            *(unsigned short*)&Wc1F8[o*EHH + k] = pk;  // Wc1F8[col][k], scaled x16
        }
    }
}

// ---------------- fused edge kernel ---------------------------------------
// grid 2048 = B*N (one i-row per block). 256 threads = 4 waves.
// waves: wm = wave>>1 (row half of 64-j chunk), wn = wave&1 (col half of 128)
__global__ __launch_bounds__(256, 3) void k_edge(
    const float* __restrict__ x,
    const float* __restrict__ hi_e,
    const unsigned short* __restrict__ hj_eb,
    const unsigned short* __restrict__ We2T,
    const unsigned char* __restrict__ Wc1F8,
    const float* __restrict__ We1,
    const float* __restrict__ be2,
    const float* __restrict__ bc1,
    const float* __restrict__ wc2,
    const float* __restrict__ bc2p,
    const int* __restrict__ radius,
    float* __restrict__ aggb, float* __restrict__ xout)
{
    __shared__ unsigned short A1[JB][136];     // silu(pre) tile, bf16, swizzled
    __shared__ unsigned short hjs[JB][136];    // hj tile, bf16, swizzled
    __shared__ unsigned char  mA8[JB][136];    // m tile, fp8 (x8 scale)
    __shared__ float dxs[JB][4];               // dx0,dx1,dx2,d2
    __shared__ float mfs[JB];                  // mask as float
    __shared__ float his[HH], w3s[HH];
    __shared__ float be2s[HH], bc1s[HH], wc2s[HH];
    __shared__ float gates[2][JB];
    __shared__ float aggp[2][HH];

    const int tid  = threadIdx.x;
    const int lane = tid & 63;
    const int wave = tid >> 6;
    const int l15  = lane & 15;
    const int g    = lane >> 4;
    const int wm   = wave >> 1, wn = wave & 1;

    const int b = blockIdx.x >> 9;
    const int i = blockIdx.x & (NN-1);
    const int base = b*NN;

    if (tid < HH){
        his[tid]  = hi_e[(base + i)*EHH + tid];
        w3s[tid]  = We1[2*HH*EHH + tid];
        be2s[tid] = be2[tid];
        bc1s[tid] = bc1[tid];
        wc2s[tid] = wc2[tid];
    }
    const float xi0 = x[(base+i)*3+0];
    const float xi1 = x[(base+i)*3+1];
    const float xi2 = x[(base+i)*3+2];
    const int   rad = radius[0];
    const float r2  = (float)(rad*rad);
    const float bc2v = bc2p[0];

    // persistent B fragments: bW1 bf16 (64 regs), bW2 fp8 (32 regs)
    short8 bW1[4][4];
    long   bW2[4][4];
    #pragma unroll
    for (int nt = 0; nt < 4; ++nt){
        const int col = wn*64 + nt*16 + l15;
        #pragma unroll
        for (int ks = 0; ks < 4; ++ks){
            bW1[nt][ks] = *(const short8*)&We2T[col*EHH + ks*32 + g*8];
            bW2[nt][ks] = *(const long*)&Wc1F8[col*EHH + ks*32 + g*8];
        }
    }

    float agg[4] = {0.f, 0.f, 0.f, 0.f};
    float cx = 0.f, cy = 0.f, cz = 0.f, cw = 0.f;

    #pragma unroll 1
    for (int c = 0; c < NCH; ++c){
        const int j0 = c*JB;
        // -------- stage hj tile (bf16, swizzled) + per-row geometry -------
        #pragma unroll
        for (int it = 0; it < 4; ++it){
            int f = it*2048 + tid*8;
            int r = f >> 7, cc = f & 127;
            *(short8*)&hjs[r][cc ^ (((r>>3)&1)<<3)] =
                *(const short8*)&hj_eb[(base + j0 + r)*EHH + cc];
        }
        if (tid < JB){
            const int jr = tid;
            float d0 = xi0 - x[(base + j0 + jr)*3 + 0];
            float d1 = xi1 - x[(base + j0 + jr)*3 + 1];
            float d2c = xi2 - x[(base + j0 + jr)*3 + 2];
            float d2v = d0*d0 + d1*d1 + d2c*d2c;
            float mf = (d2v < r2 && (j0 + jr) != i) ? 1.f : 0.f;
            dxs[jr][0] = d0; dxs[jr][1] = d1; dxs[jr][2] = d2c; dxs[jr][3] = d2v;
            mfs[jr] = mf;
        }
        __syncthreads();                       // B1

        // -------- cooperative A1 build: row=lane, cols wave*32..+31 -------
        {
            const int r = lane;
            const float d2v = dxs[r][3];
            const int sw = ((r>>3)&1)<<3;
            #pragma unroll
            for (int k = 0; k < 4; ++k){
                const int c0 = wave*32 + k*8;
                short8 hj8 = *(const short8*)&hjs[r][c0 ^ sw];
                f32x4 hiA = *(const f32x4*)&his[c0];
                f32x4 hiB = *(const f32x4*)&his[c0+4];
                f32x4 w3A = *(const f32x4*)&w3s[c0];
                f32x4 w3B = *(const f32x4*)&w3s[c0+4];
                float p[8];
                #pragma unroll
                for (int e = 0; e < 4; ++e){
                    float hv0 = __uint_as_float(((unsigned int)(unsigned short)hj8[e]) << 16);
                    float hv1 = __uint_as_float(((unsigned int)(unsigned short)hj8[e+4]) << 16);
                    p[e]   = fsilu(hiA[e] + hv0 + d2v*w3A[e]);
                    p[e+4] = fsilu(hiB[e] + hv1 + d2v*w3B[e]);
                }
                short8 outv;
                ((unsigned int*)&outv)[0] = cvt_pk_bf16(p[0], p[1]);
                ((unsigned int*)&outv)[1] = cvt_pk_bf16(p[2], p[3]);
                ((unsigned int*)&outv)[2] = cvt_pk_bf16(p[4], p[5]);
                ((unsigned int*)&outv)[3] = cvt_pk_bf16(p[6], p[7]);
                *(short8*)&A1[r][c0 ^ sw] = outv;
            }
        }
        __syncthreads();                       // B2

        // -------- GEMM1: m_pre = A1 @ We2 ---------------------------------
        f32x4 acc[2][4];
        #pragma unroll
        for (int mt = 0; mt < 2; ++mt)
            #pragma unroll
            for (int nt = 0; nt < 4; ++nt) acc[mt][nt] = (f32x4){0.f,0.f,0.f,0.f};

        #pragma unroll
        for (int ks = 0; ks < 4; ++ks){
            short8 afr[2];
            #pragma unroll
            for (int mt = 0; mt < 2; ++mt){
                const int row = wm*32 + mt*16 + l15;
                const int c0 = ks*32 + g*8;
                afr[mt] = *(const short8*)&A1[row][c0 ^ (((row>>3)&1)<<3)];
            }
            #pragma unroll
            for (int nt = 0; nt < 4; ++nt)
                #pragma unroll
                for (int mt = 0; mt < 2; ++mt)
                    acc[mt][nt] = __builtin_amdgcn_mfma_f32_16x16x32_bf16(
                        afr[mt], bW1[nt][ks], acc[mt][nt], 0, 0, 0);
        }

        // -------- epilogue 1: m = silu(acc+be2)*mask; agg += m; mA8 = m*8 -
        #pragma unroll
        for (int mt = 0; mt < 2; ++mt){
            float mfr[4];
            #pragma unroll
            for (int rg = 0; rg < 4; ++rg)
                mfr[rg] = mfs[wm*32 + mt*16 + g*4 + rg];
            #pragma unroll
            for (int nt = 0; nt < 4; ++nt){
                const int col = wn*64 + nt*16 + l15;
                const float bb = be2s[col];
                f32x4 v = acc[mt][nt];
                #pragma unroll
                for (int rg = 0; rg < 4; ++rg){
                    const int row = wm*32 + mt*16 + g*4 + rg;
                    float m = fsilu(v[rg] + bb) * mfr[rg];
                    agg[nt] += m;
                    mA8[row][col] = f2fp8(m * 8.f);
                }
            }
        }
        __syncthreads();                       // B3

        // -------- GEMM2 (fp8): g1_pre = m @ Wc1 ---------------------------
        f32x4 acc2[2][4];
        #pragma unroll
        for (int mt = 0; mt < 2; ++mt)
            #pragma unroll
            for (int nt = 0; nt < 4; ++nt) acc2[mt][nt] = (f32x4){0.f,0.f,0.f,0.f};

        #pragma unroll
        for (int ks = 0; ks < 4; ++ks){
            long a8[2];
            #pragma unroll
            for (int mt = 0; mt < 2; ++mt){
                const int row = wm*32 + mt*16 + l15;
                a8[mt] = *(const long*)&mA8[row][ks*32 + g*8];
            }
            #pragma unroll
            for (int nt = 0; nt < 4; ++nt)
                #pragma unroll
                for (int mt = 0; mt < 2; ++mt)
                    acc2[mt][nt] = __builtin_amdgcn_mfma_f32_16x16x32_fp8_fp8(
                        a8[mt], bW2[nt][ks], acc2[mt][nt], 0, 0, 0);
        }

        // -------- epilogue 2: gate partials -------------------------------
        float gp[2][4];
        #pragma unroll
        for (int mt = 0; mt < 2; ++mt)
            #pragma unroll
            for (int rg = 0; rg < 4; ++rg) gp[mt][rg] = 0.f;
        #pragma unroll
        for (int mt = 0; mt < 2; ++mt){
            #pragma unroll
            for (int nt = 0; nt < 4; ++nt){
                const int col = wn*64 + nt*16 + l15;
                const float bcv = bc1s[col], wcv = wc2s[col];
                f32x4 v = acc2[mt][nt];
                #pragma unroll
                for (int rg = 0; rg < 4; ++rg)
                    gp[mt][rg] += fsilu(v[rg]*(1.f/128.f) + bcv) * wcv;
            }
        }
        #pragma unroll
        for (int mt = 0; mt < 2; ++mt){
            #pragma unroll
            for (int rg = 0; rg < 4; ++rg){
                float t = gp[mt][rg];
                t += __shfl_xor(t, 1); t += __shfl_xor(t, 2);
                t += __shfl_xor(t, 4); t += __shfl_xor(t, 8);
                gp[mt][rg] = t;
            }
        }
        if (l15 == 0){
            #pragma unroll
            for (int mt = 0; mt < 2; ++mt)
                #pragma unroll
                for (int rg = 0; rg < 4; ++rg)
                    gates[wn][wm*32 + mt*16 + g*4 + rg] = gp[mt][rg];
        }
        __syncthreads();                       // B4

        // -------- coord accumulation (wave 0, per-lane accumulators) ------
        if (wave == 0){
            const int r = lane;
            float gt = gates[0][r] + gates[1][r] + bc2v;
            float mf = mfs[r];
            float gv = gt * mf;
            cx += dxs[r][0]*gv; cy += dxs[r][1]*gv; cz += dxs[r][2]*gv;
            cw += mf;
        }
    }

    // -------- agg write ----------------------------------------------------
    #pragma unroll
    for (int nt = 0; nt < 4; ++nt){
        float t = agg[nt];
        t += __shfl_xor(t, 16); t += __shfl_xor(t, 32);
        agg[nt] = t;
    }
    if (lane < 16){
        #pragma unroll
        for (int nt = 0; nt < 4; ++nt)
            aggp[wm][wn*64 + nt*16 + l15] = agg[nt];
    }
    __syncthreads();
    if (tid < HH) aggb[(base + i)*HH + tid] = aggp[0][tid] + aggp[1][tid];

    // -------- x write ------------------------------------------------------
    if (wave == 0){
        #pragma unroll
        for (int m = 1; m <= 32; m <<= 1){
            cx += __shfl_xor(cx, m);
            cy += __shfl_xor(cy, m);
            cz += __shfl_xor(cz, m);
            cw += __shfl_xor(cw, m);
        }
        if (lane == 0){
            float cnt = cw > 1.f ? cw : 1.f;
            float inv = 1.0f / cnt;
            xout[(base+i)*3 + 0] = xi0 + cx*inv;
            xout[(base+i)*3 + 1] = xi1 + cy*inv;
            xout[(base+i)*3 + 2] = xi2 + cz*inv;
        }
    }
}

// ---------------- node MLP: h_new = h + MLP(concat(h, agg)) ---------------
__global__ __launch_bounds__(128) void k_node(
    const float* __restrict__ h, const float* __restrict__ aggb,
    const float* __restrict__ Wn1, const float* __restrict__ bn1,
    const float* __restrict__ Wn2, const float* __restrict__ bn2,
    float* __restrict__ hout)
{
    __shared__ float hcat[8][260];
    __shared__ float t1[8][132];
    const int tid = threadIdx.x;
    const int row0 = blockIdx.x * 8;
    #pragma unroll
    for (int r = 0; r < 8; ++r){
        hcat[r][tid]      = h[(row0 + r)*HH + tid];
        hcat[r][HH + tid] = aggb[(row0 + r)*HH + tid];
    }
    __syncthreads();
    float acc[8] = {0.f,0.f,0.f,0.f,0.f,0.f,0.f,0.f};
    #pragma unroll 4
    for (int k = 0; k < 2*HH; ++k){
        float w = Wn1[k*EHH + tid];
        #pragma unroll
        for (int r = 0; r < 8; ++r) acc[r] += hcat[r][k] * w;
    }
    const float bn1v = bn1[tid];
    #pragma unroll
    for (int r = 0; r < 8; ++r) t1[r][tid] = fsilu(acc[r] + bn1v);
    __syncthreads();
    float acc2[8] = {0.f,0.f,0.f,0.f,0.f,0.f,0.f,0.f};
    #pragma unroll 4
    for (int e = 0; e < EHH; ++e){
        float w = Wn2[e*HH + tid];
        #pragma unroll
        for (int r = 0; r < 8; ++r) acc2[r] += t1[r][e] * w;
    }
    const float bn2v = bn2[tid];
    #pragma unroll
    for (int r = 0; r < 8; ++r)
        hout[(row0 + r)*HH + tid] = hcat[r][tid] + acc2[r] + bn2v;
}

extern "C" void kernel_launch(void* const* d_in, const int* in_sizes, int n_in,
                              void* d_out, int out_size, void* d_ws, size_t ws_size,
                              hipStream_t stream) {
    const float* h   = (const float*)d_in[0];
    const float* x   = (const float*)d_in[1];
    const float* We1 = (const float*)d_in[2];
    const float* be1 = (const float*)d_in[3];
    const float* We2 = (const float*)d_in[4];
    const float* be2 = (const float*)d_in[5];
    const float* Wc1 = (const float*)d_in[6];
    const float* bc1 = (const float*)d_in[7];
    const float* Wc2 = (const float*)d_in[8];
    const float* bc2 = (const float*)d_in[9];
    const float* Wn1 = (const float*)d_in[10];
    const float* bn1 = (const float*)d_in[11];
    const float* Wn2 = (const float*)d_in[12];
    const float* bn2 = (const float*)d_in[13];
    const int* radius = (const int*)d_in[14];

    float* out_h = (float*)d_out;
    float* out_x = out_h + BB*NN*HH;

    char* ws = (char*)d_ws;
    float*          hi_e  = (float*)ws;                              // 1 MB
    unsigned short* hj_eb = (unsigned short*)(ws + (1u<<20));        // 512 KB
    unsigned short* We2T  = (unsigned short*)(ws + (1u<<20) + (512u<<10));   // 32 KB
    unsigned char*  Wc1F8 = (unsigned char*)(ws + (1u<<20) + (544u<<10));    // 16 KB
    float*          aggb  = (float*)(ws + (1u<<20) + (560u<<10));    // 1 MB

    k_prep<<<BB*NN + 32, 128, 0, stream>>>(h, We1, be1, We2, Wc1,
                                           hi_e, hj_eb, We2T, Wc1F8);
    k_edge<<<BB*NN, 256, 0, stream>>>(x, hi_e, hj_eb, We2T, Wc1F8,
                                      We1, be2, bc1, Wc2, bc2, radius,
                                      aggb, out_x);
    k_node<<<BB*NN/8, 128, 0, stream>>>(h, aggb, Wn1, bn1, Wn2, bn2, out_h);
}

// Round 4
// 297.836 us; speedup vs baseline: 1.5277x; 1.5277x over previous
//
#include <hip/hip_runtime.h>

#define BB 4
#define NN 512
#define HH 128
#define EHH 128
#define JB 64
#define NCH (NN/JB)

typedef short short8 __attribute__((ext_vector_type(8)));
typedef float f32x4 __attribute__((ext_vector_type(4)));

__device__ __forceinline__ float fsilu(float x){
    float e = __expf(-x);
    return x * __builtin_amdgcn_rcpf(1.0f + e);
}

__device__ __forceinline__ unsigned int cvt_pk_bf16(float lo, float hi){
    unsigned int r;
    asm("v_cvt_pk_bf16_f32 %0, %1, %2" : "=v"(r) : "v"(lo), "v"(hi));
    return r;
}

__device__ __forceinline__ unsigned short f2bf(float f){
    return (unsigned short)(cvt_pk_bf16(f, 0.f) & 0xffffu);
}

__device__ __forceinline__ unsigned char f2fp8(float f){
#if __has_builtin(__builtin_amdgcn_cvt_pk_fp8_f32)
    int r = __builtin_amdgcn_cvt_pk_fp8_f32(f, 0.f, 0, false);
    return (unsigned char)(r & 0xff);
#else
    unsigned int u = __float_as_uint(f);
    unsigned int sign = (u >> 24) & 0x80;
    float a = fabsf(f);
    if (!(a > 0.f)) return (unsigned char)sign;
    if (a >= 448.f) return (unsigned char)(sign | 0x7E);
    int e = (int)((u >> 23) & 0xFF) - 127;
    if (e < -6){
        int m = (int)(a * 512.f + 0.5f);
        return (unsigned char)(sign | m);
    }
    unsigned int mant = (u >> 20) & 0x7;
    unsigned int rest = u & 0xFFFFF;
    unsigned int exp8 = (unsigned int)(e + 7);
    if (rest > 0x80000 || (rest == 0x80000 && (mant & 1))){
        mant++;
        if (mant == 8){ mant = 0; exp8++; }
    }
    if (exp8 >= 16) return (unsigned char)(sign | 0x7E);
    return (unsigned char)(sign | (exp8 << 3) | mant);
#endif
}

// ---------------- prep: projections + weight conversions ------------------
__global__ __launch_bounds__(128) void k_prep(
    const float* __restrict__ h,
    const float* __restrict__ We1, const float* __restrict__ be1,
    const float* __restrict__ We2, const float* __restrict__ Wc1,
    float* __restrict__ hi_e, unsigned short* __restrict__ hj_eb,
    unsigned short* __restrict__ We2T, unsigned char* __restrict__ Wc1F8)
{
    const int tid = threadIdx.x;
    if (blockIdx.x < BB*NN) {
        __shared__ float hrow[HH];
        const int row = blockIdx.x;
        hrow[tid] = h[row*HH + tid];
        __syncthreads();
        float a0 = be1[tid];   // fold be1 into hi_e
        float a1 = 0.f;
        #pragma unroll 8
        for (int k = 0; k < HH; ++k){
            float hv = hrow[k];
            a0 += hv * We1[k*EHH + tid];
            a1 += hv * We1[(HH + k)*EHH + tid];
        }
        hi_e[row*EHH + tid] = a0;
        hj_eb[row*EHH + tid] = f2bf(a1);
    } else {
        const int bid = blockIdx.x - BB*NN;   // 0..31
        for (int t = bid*128 + tid; t < 128*128; t += 32*128){
            int o = t >> 7, kk = t & 127;
            We2T[t] = f2bf(We2[kk*HH + o]);          // We2T[col][k]
        }
        for (int idx = bid*128 + tid; idx < 8192; idx += 32*128){
            int o = idx >> 6, kp = idx & 63;
            int k = 2*kp;
            float f0 = Wc1[k*EHH + o] * 16.f;
            float f1 = Wc1[(k+1)*EHH + o] * 16.f;
            unsigned short pk = (unsigned short)(f2fp8(f0) | ((unsigned short)f2fp8(f1) << 8));
            *(unsigned short*)&Wc1F8[o*EHH + k] = pk;  // Wc1F8[col][k], scaled x16
        }
    }
}

// ---------------- fused edge kernel ---------------------------------------
// grid 2048 = B*N (one i-row per block). 256 threads = 4 waves (wm x wn = 2x2)
__global__ __launch_bounds__(256, 2) void k_edge(
    const float* __restrict__ x,
    const float* __restrict__ hi_e,
    const unsigned short* __restrict__ hj_eb,
    const unsigned short* __restrict__ We2T,
    const unsigned char* __restrict__ Wc1F8,
    const float* __restrict__ We1,
    const float* __restrict__ be2,
    const float* __restrict__ bc1,
    const float* __restrict__ wc2,
    const float* __restrict__ bc2p,
    const int* __restrict__ radius,
    float* __restrict__ aggb, float* __restrict__ xout)
{
    __shared__ unsigned short A1[JB][136];   // silu(pre) tile, bf16, swizzled
    __shared__ unsigned char  mA8[JB][136];  // m tile, fp8 (x8 scale)
    __shared__ float dxs[2][JB][4];          // dx0,dx1,dx2,mask (dbuf)
    __shared__ float his[HH], w3s[HH];
    __shared__ float aggp[2][HH];
    __shared__ float cred[4][4];

    const int tid  = threadIdx.x;
    const int lane = tid & 63;
    const int wave = tid >> 6;
    const int l15  = lane & 15;
    const int g    = lane >> 4;
    const int wm   = wave >> 1, wn = wave & 1;

    const int b = blockIdx.x >> 9;
    const int i = blockIdx.x & (NN-1);
    const int base = b*NN;

    if (tid < HH){
        his[tid] = hi_e[(base + i)*EHH + tid];
        w3s[tid] = We1[2*HH*EHH + tid];
    }
    const float xi0 = x[(base+i)*3+0];
    const float xi1 = x[(base+i)*3+1];
    const float xi2 = x[(base+i)*3+2];
    const int   rad = radius[0];
    const float r2  = (float)(rad*rad);
    const float bc2v = bc2p[0];

    // per-lane epilogue constants
    float be2r[4], bc1r[4], wc2r[4];
    #pragma unroll
    for (int nt = 0; nt < 4; ++nt){
        const int col = wn*64 + nt*16 + l15;
        be2r[nt] = be2[col];
        bc1r[nt] = bc1[col];
        wc2r[nt] = wc2[col];
    }

    // persistent B fragments: bW1 bf16 (64 regs), bW2 fp8 (32 regs)
    short8 bW1[4][4];
    long   bW2[4][4];
    #pragma unroll
    for (int nt = 0; nt < 4; ++nt){
        const int col = wn*64 + nt*16 + l15;
        #pragma unroll
        for (int ks = 0; ks < 4; ++ks){
            bW1[nt][ks] = *(const short8*)&We2T[col*EHH + ks*32 + g*8];
            bW2[nt][ks] = *(const long*)&Wc1F8[col*EHH + ks*32 + g*8];
        }
    }

    float agg[4] = {0.f, 0.f, 0.f, 0.f};
    float cx = 0.f, cy = 0.f, cz = 0.f, cw = 0.f;

    // pipelined hj/xj loads for chunk 0
    short8 hjn[4];
    float xjn0, xjn1, xjn2;
    {
        const int gj = 0 + lane;
        #pragma unroll
        for (int k = 0; k < 4; ++k)
            hjn[k] = *(const short8*)&hj_eb[(base + gj)*EHH + wave*32 + k*8];
        xjn0 = x[(base+gj)*3+0];
        xjn1 = x[(base+gj)*3+1];
        xjn2 = x[(base+gj)*3+2];
    }

    __syncthreads();                          // his/w3s ready

    #pragma unroll 1
    for (int c = 0; c < NCH; ++c){
        const int j0 = c*JB;
        const int buf = c & 1;
        const int r = lane;
        const int gj = j0 + r;

        // -------- phase A: geometry + A1 build (from pipelined regs) ------
        float d0 = xi0 - xjn0;
        float d1 = xi1 - xjn1;
        float d2c = xi2 - xjn2;
        float d2v = d0*d0 + d1*d1 + d2c*d2c;
        float mf = (d2v < r2 && gj != i) ? 1.f : 0.f;
        if (wave == 0){
            dxs[buf][r][0] = d0; dxs[buf][r][1] = d1;
            dxs[buf][r][2] = d2c; dxs[buf][r][3] = mf;
            cw += mf;
            float t = mf * bc2v;
            cx += d0*t; cy += d1*t; cz += d2c*t;
        }
        const int sw = ((r>>3)&1)<<3;
        #pragma unroll
        for (int k = 0; k < 4; ++k){
            const int c0 = wave*32 + k*8;
            short8 hj8 = hjn[k];
            f32x4 hiA = *(const f32x4*)&his[c0];
            f32x4 hiB = *(const f32x4*)&his[c0+4];
            f32x4 w3A = *(const f32x4*)&w3s[c0];
            f32x4 w3B = *(const f32x4*)&w3s[c0+4];
            float p[8];
            #pragma unroll
            for (int e = 0; e < 4; ++e){
                float hv0 = __uint_as_float(((unsigned int)(unsigned short)hj8[e]) << 16);
                float hv1 = __uint_as_float(((unsigned int)(unsigned short)hj8[e+4]) << 16);
                p[e]   = fsilu(hiA[e] + hv0 + d2v*w3A[e]);
                p[e+4] = fsilu(hiB[e] + hv1 + d2v*w3B[e]);
            }
            short8 outv;
            ((unsigned int*)&outv)[0] = cvt_pk_bf16(p[0], p[1]);
            ((unsigned int*)&outv)[1] = cvt_pk_bf16(p[2], p[3]);
            ((unsigned int*)&outv)[2] = cvt_pk_bf16(p[4], p[5]);
            ((unsigned int*)&outv)[3] = cvt_pk_bf16(p[6], p[7]);
            *(short8*)&A1[r][c0 ^ sw] = outv;
        }
        // issue next chunk's loads (land during GEMM1+GEMM2)
        if (c + 1 < NCH){
            const int gj2 = j0 + JB + lane;
            #pragma unroll
            for (int k = 0; k < 4; ++k)
                hjn[k] = *(const short8*)&hj_eb[(base + gj2)*EHH + wave*32 + k*8];
            xjn0 = x[(base+gj2)*3+0];
            xjn1 = x[(base+gj2)*3+1];
            xjn2 = x[(base+gj2)*3+2];
        }
        __syncthreads();                      // B2: A1/dxs ready

        // -------- GEMM1: m_pre = A1 @ We2 ---------------------------------
        f32x4 acc[2][4];
        #pragma unroll
        for (int mt = 0; mt < 2; ++mt)
            #pragma unroll
            for (int nt = 0; nt < 4; ++nt) acc[mt][nt] = (f32x4){0.f,0.f,0.f,0.f};

        const int swr = ((l15>>3)&1)<<3;
        #pragma unroll
        for (int ks = 0; ks < 4; ++ks){
            short8 afr[2];
            #pragma unroll
            for (int mt = 0; mt < 2; ++mt){
                const int row = wm*32 + mt*16 + l15;
                afr[mt] = *(const short8*)&A1[row][(ks*32 + g*8) ^ swr];
            }
            #pragma unroll
            for (int nt = 0; nt < 4; ++nt)
                #pragma unroll
                for (int mt = 0; mt < 2; ++mt)
                    acc[mt][nt] = __builtin_amdgcn_mfma_f32_16x16x32_bf16(
                        afr[mt], bW1[nt][ks], acc[mt][nt], 0, 0, 0);
        }

        // -------- epi1: m = silu(acc+be2)*mask; agg += m; mA8 = m*8 -------
        #pragma unroll
        for (int mt = 0; mt < 2; ++mt){
            float mfr[4];
            #pragma unroll
            for (int rg = 0; rg < 4; ++rg)
                mfr[rg] = dxs[buf][wm*32 + mt*16 + g*4 + rg][3];
            #pragma unroll
            for (int nt = 0; nt < 4; ++nt){
                const int col = wn*64 + nt*16 + l15;
                f32x4 v = acc[mt][nt];
                #pragma unroll
                for (int rg = 0; rg < 4; ++rg){
                    const int row = wm*32 + mt*16 + g*4 + rg;
                    float m = fsilu(v[rg] + be2r[nt]) * mfr[rg];
                    agg[nt] += m;
                    mA8[row][col] = f2fp8(m * 8.f);
                }
            }
        }
        __syncthreads();                      // B3: mA8 ready

        // -------- GEMM2 (fp8): g1_pre = m @ Wc1 ---------------------------
        f32x4 acc2[2][4];
        #pragma unroll
        for (int mt = 0; mt < 2; ++mt)
            #pragma unroll
            for (int nt = 0; nt < 4; ++nt) acc2[mt][nt] = (f32x4){0.f,0.f,0.f,0.f};

        #pragma unroll
        for (int ks = 0; ks < 4; ++ks){
            long a8[2];
            #pragma unroll
            for (int mt = 0; mt < 2; ++mt){
                const int row = wm*32 + mt*16 + l15;
                a8[mt] = *(const long*)&mA8[row][ks*32 + g*8];
            }
            #pragma unroll
            for (int nt = 0; nt < 4; ++nt)
                #pragma unroll
                for (int mt = 0; mt < 2; ++mt)
                    acc2[mt][nt] = __builtin_amdgcn_mfma_f32_16x16x32_fp8_fp8(
                        a8[mt], bW2[nt][ks], acc2[mt][nt], 0, 0, 0);
        }

        // -------- epi2: gate partials + per-lane coord accumulation -------
        float gp[2][4];
        #pragma unroll
        for (int mt = 0; mt < 2; ++mt)
            #pragma unroll
            for (int rg = 0; rg < 4; ++rg) gp[mt][rg] = 0.f;
        #pragma unroll
        for (int mt = 0; mt < 2; ++mt)
            #pragma unroll
            for (int nt = 0; nt < 4; ++nt){
                f32x4 v = acc2[mt][nt];
                #pragma unroll
                for (int rg = 0; rg < 4; ++rg)
                    gp[mt][rg] += fsilu(v[rg]*(1.f/128.f) + bc1r[nt]) * wc2r[nt];
            }
        #pragma unroll
        for (int mt = 0; mt < 2; ++mt)
            #pragma unroll
            for (int rg = 0; rg < 4; ++rg){
                const int row = wm*32 + mt*16 + g*4 + rg;
                f32x4 dv = *(const f32x4*)&dxs[buf][row][0];
                float gv = gp[mt][rg] * dv[3];
                cx += dv[0]*gv; cy += dv[1]*gv; cz += dv[2]*gv;
            }
        // no barrier: next phase A writes A1 (reads done pre-B3) and dxs[buf^1]
    }

    // -------- agg write ----------------------------------------------------
    #pragma unroll
    for (int nt = 0; nt < 4; ++nt){
        float t = agg[nt];
        t += __shfl_xor(t, 16); t += __shfl_xor(t, 32);
        agg[nt] = t;
    }
    if (lane < 16){
        #pragma unroll
        for (int nt = 0; nt < 4; ++nt)
            aggp[wm][wn*64 + nt*16 + l15] = agg[nt];
    }

    // -------- coord cross-wave reduce -------------------------------------
    #pragma unroll
    for (int m = 1; m <= 32; m <<= 1){
        cx += __shfl_xor(cx, m);
        cy += __shfl_xor(cy, m);
        cz += __shfl_xor(cz, m);
        cw += __shfl_xor(cw, m);
    }
    if (lane == 0){
        cred[wave][0] = cx; cred[wave][1] = cy;
        cred[wave][2] = cz; cred[wave][3] = cw;
    }
    __syncthreads();
    if (tid < HH) aggb[(base + i)*HH + tid] = aggp[0][tid] + aggp[1][tid];
    if (tid == 0){
        float sx = cred[0][0] + cred[1][0] + cred[2][0] + cred[3][0];
        float sy = cred[0][1] + cred[1][1] + cred[2][1] + cred[3][1];
        float sz = cred[0][2] + cred[1][2] + cred[2][2] + cred[3][2];
        float sw_ = cred[0][3] + cred[1][3] + cred[2][3] + cred[3][3];
        float cnt = sw_ > 1.f ? sw_ : 1.f;
        float inv = 1.0f / cnt;
        xout[(base+i)*3 + 0] = xi0 + sx*inv;
        xout[(base+i)*3 + 1] = xi1 + sy*inv;
        xout[(base+i)*3 + 2] = xi2 + sz*inv;
    }
}

// ---------------- node MLP: h_new = h + MLP(concat(h, agg)) ---------------
__global__ __launch_bounds__(128) void k_node(
    const float* __restrict__ h, const float* __restrict__ aggb,
    const float* __restrict__ Wn1, const float* __restrict__ bn1,
    const float* __restrict__ Wn2, const float* __restrict__ bn2,
    float* __restrict__ hout)
{
    __shared__ float hcat[8][260];
    __shared__ float t1[8][132];
    const int tid = threadIdx.x;
    const int row0 = blockIdx.x * 8;
    #pragma unroll
    for (int r = 0; r < 8; ++r){
        hcat[r][tid]      = h[(row0 + r)*HH + tid];
        hcat[r][HH + tid] = aggb[(row0 + r)*HH + tid];
    }
    __syncthreads();
    float acc[8] = {0.f,0.f,0.f,0.f,0.f,0.f,0.f,0.f};
    #pragma unroll 4
    for (int k = 0; k < 2*HH; ++k){
        float w = Wn1[k*EHH + tid];
        #pragma unroll
        for (int r = 0; r < 8; ++r) acc[r] += hcat[r][k] * w;
    }
    const float bn1v = bn1[tid];
    #pragma unroll
    for (int r = 0; r < 8; ++r) t1[r][tid] = fsilu(acc[r] + bn1v);
    __syncthreads();
    float acc2[8] = {0.f,0.f,0.f,0.f,0.f,0.f,0.f,0.f};
    #pragma unroll 4
    for (int e = 0; e < EHH; ++e){
        float w = Wn2[e*HH + tid];
        #pragma unroll
        for (int r = 0; r < 8; ++r) acc2[r] += t1[r][e] * w;
    }
    const float bn2v = bn2[tid];
    #pragma unroll
    for (int r = 0; r < 8; ++r)
        hout[(row0 + r)*HH + tid] = hcat[r][tid] + acc2[r] + bn2v;
}

extern "C" void kernel_launch(void* const* d_in, const int* in_sizes, int n_in,
                              void* d_out, int out_size, void* d_ws, size_t ws_size,
                              hipStream_t stream) {
    const float* h   = (const float*)d_in[0];
    const float* x   = (const float*)d_in[1];
    const float* We1 = (const float*)d_in[2];
    const float* be1 = (const float*)d_in[3];
    const float* We2 = (const float*)d_in[4];
    const float* be2 = (const float*)d_in[5];
    const float* Wc1 = (const float*)d_in[6];
    const float* bc1 = (const float*)d_in[7];
    const float* Wc2 = (const float*)d_in[8];
    const float* bc2 = (const float*)d_in[9];
    const float* Wn1 = (const float*)d_in[10];
    const float* bn1 = (const float*)d_in[11];
    const float* Wn2 = (const float*)d_in[12];
    const float* bn2 = (const float*)d_in[13];
    const int* radius = (const int*)d_in[14];

    float* out_h = (float*)d_out;
    float* out_x = out_h + BB*NN*HH;

    char* ws = (char*)d_ws;
    float*          hi_e  = (float*)ws;                              // 1 MB
    unsigned short* hj_eb = (unsigned short*)(ws + (1u<<20));        // 512 KB
    unsigned short* We2T  = (unsigned short*)(ws + (1u<<20) + (512u<<10));   // 32 KB
    unsigned char*  Wc1F8 = (unsigned char*)(ws + (1u<<20) + (544u<<10));    // 16 KB
    float*          aggb  = (float*)(ws + (1u<<20) + (560u<<10));    // 1 MB

    k_prep<<<BB*NN + 32, 128, 0, stream>>>(h, We1, be1, We2, Wc1,
                                           hi_e, hj_eb, We2T, Wc1F8);
    k_edge<<<BB*NN, 256, 0, stream>>>(x, hi_e, hj_eb, We2T, Wc1F8,
                                      We1, be2, bc1, Wc2, bc2, radius,
                                      aggb, out_x);
    k_node<<<BB*NN/8, 128, 0, stream>>>(h, aggb, Wn1, bn1, Wn2, bn2, out_h);
}

// Round 6
// 236.782 us; speedup vs baseline: 1.9217x; 1.2578x over previous
//
#include <hip/hip_runtime.h>

#define BB 4
#define NN 512
#define HH 128
#define EHH 128
#define JB 64

typedef short short8 __attribute__((ext_vector_type(8)));
typedef float f32x4 __attribute__((ext_vector_type(4)));

__device__ __forceinline__ float fsilu(float x){
    float e = __expf(-x);
    return x * __builtin_amdgcn_rcpf(1.0f + e);
}

__device__ __forceinline__ unsigned int cvt_pk_bf16(float lo, float hi){
    unsigned int r;
    asm("v_cvt_pk_bf16_f32 %0, %1, %2" : "=v"(r) : "v"(lo), "v"(hi));
    return r;
}

__device__ __forceinline__ unsigned short f2bf(float f){
    return (unsigned short)(cvt_pk_bf16(f, 0.f) & 0xffffu);
}

// packed fp8 e4m3 convert: byte0 = cvt(lo), byte1 = cvt(hi)
__device__ __forceinline__ unsigned int cvt_pk_fp8(float lo, float hi){
    unsigned int r;
    asm("v_cvt_pk_fp8_f32 %0, %1, %2" : "=v"(r) : "v"(lo), "v"(hi));
    return r;
}

// ---------------- prep: projections + weight conversions ------------------
// grid: 256 row-blocks (8 rows each) + 16 weight-conversion blocks
__global__ __launch_bounds__(256) void k_prep(
    const float* __restrict__ h,
    const float* __restrict__ We1, const float* __restrict__ be1,
    const float* __restrict__ We2, const float* __restrict__ Wc1,
    float* __restrict__ hi_e, unsigned short* __restrict__ hj_eb,
    unsigned short* __restrict__ We2T, unsigned char* __restrict__ Wc1F8)
{
    const int tid = threadIdx.x;
    if (blockIdx.x < BB*NN/8) {
        __shared__ float hrows[8][HH];
        const int row0 = blockIdx.x * 8;
        #pragma unroll
        for (int t = tid; t < 8*HH; t += 256)
            hrows[t >> 7][t & 127] = h[row0*HH + t];
        __syncthreads();
        const int col  = tid & 127;
        const int half = tid >> 7;           // 0: hi (We1[0:128]), 1: hj (We1[128:256])
        float acc[8] = {0.f,0.f,0.f,0.f,0.f,0.f,0.f,0.f};
        #pragma unroll 4
        for (int k = 0; k < HH; ++k){
            float w = We1[(half*HH + k)*EHH + col];
            #pragma unroll
            for (int r = 0; r < 8; ++r) acc[r] += hrows[r][k] * w;
        }
        if (half == 0){
            const float bb = be1[col];
            #pragma unroll
            for (int r = 0; r < 8; ++r)
                hi_e[(row0 + r)*EHH + col] = acc[r] + bb;
        } else {
            #pragma unroll
            for (int r = 0; r < 8; ++r)
                hj_eb[(row0 + r)*EHH + col] = f2bf(acc[r]);
        }
    } else {
        const int bid = blockIdx.x - BB*NN/8;   // 0..15
        for (int t = bid*256 + tid; t < 128*128; t += 16*256){
            int o = t >> 7, kk = t & 127;
            We2T[t] = f2bf(We2[kk*HH + o]);          // We2T[col][k]
        }
        for (int idx = bid*256 + tid; idx < 8192; idx += 16*256){
            int o = idx >> 6, kp = idx & 63;
            int k = 2*kp;
            unsigned int pk = cvt_pk_fp8(Wc1[k*EHH + o] * 16.f,
                                         Wc1[(k+1)*EHH + o] * 16.f);
            *(unsigned short*)&Wc1F8[o*EHH + k] = (unsigned short)(pk & 0xffffu);
        }
    }
}

// ---------------- fused edge kernel (neighbor-compacted) -------------------
// grid 2048 = B*N (one i-row per block). 256 threads = 4 waves (wm x wn = 2x2)
__global__ __launch_bounds__(256, 2) void k_edge(
    const float* __restrict__ x,
    const float* __restrict__ hi_e,
    const unsigned short* __restrict__ hj_eb,
    const unsigned short* __restrict__ We2T,
    const unsigned char* __restrict__ Wc1F8,
    const float* __restrict__ We1,
    const float* __restrict__ be2,
    const float* __restrict__ bc1,
    const float* __restrict__ wc2,
    const float* __restrict__ bc2p,
    const int* __restrict__ radius,
    float* __restrict__ aggb, float* __restrict__ xout)
{
    __shared__ unsigned short A1[JB][136];   // silu(pre) tile, bf16, swizzled
    __shared__ unsigned char  mA8[JB][136];  // m tile, fp8 (x8 scale)
    __shared__ float dxs[2][JB][4];          // dx0,dx1,dx2,mask (dbuf)
    __shared__ float his[HH], w3s[HH];
    __shared__ float aggp[2][HH];
    __shared__ float cred[4][3];
    __shared__ unsigned short jseg[4][128];
    __shared__ unsigned short jlist[NN];
    __shared__ int cnts[4];

    const int tid  = threadIdx.x;
    const int lane = tid & 63;
    const int wave = tid >> 6;
    const int l15  = lane & 15;
    const int g    = lane >> 4;
    const int wm   = wave >> 1, wn = wave & 1;

    const int b = blockIdx.x >> 9;
    const int i = blockIdx.x & (NN-1);
    const int base = b*NN;

    if (tid < HH){
        his[tid] = hi_e[(base + i)*EHH + tid];
        w3s[tid] = We1[2*HH*EHH + tid];
    }
    const float xi0 = x[(base+i)*3+0];
    const float xi1 = x[(base+i)*3+1];
    const float xi2 = x[(base+i)*3+2];
    const int   rad = radius[0];
    const float r2  = (float)(rad*rad);
    const float bc2v = bc2p[0];

    // per-lane epilogue constants
    float be2r[4], bc1r[4], wc2r[4];
    #pragma unroll
    for (int nt = 0; nt < 4; ++nt){
        const int col = wn*64 + nt*16 + l15;
        be2r[nt] = be2[col];
        bc1r[nt] = bc1[col];
        wc2r[nt] = wc2[col];
    }

    // persistent B fragments: bW1 bf16 (64 regs), bW2 fp8 (32 regs)
    short8 bW1[4][4];
    long   bW2[4][4];
    #pragma unroll
    for (int nt = 0; nt < 4; ++nt){
        const int col = wn*64 + nt*16 + l15;
        #pragma unroll
        for (int ks = 0; ks < 4; ++ks){
            bW1[nt][ks] = *(const short8*)&We2T[col*EHH + ks*32 + g*8];
            bW2[nt][ks] = *(const long*)&Wc1F8[col*EHH + ks*32 + g*8];
        }
    }

    // -------- neighbor compaction: wave w owns j in [w*128,(w+1)*128) -----
    int wcnt = 0;
    #pragma unroll
    for (int t = 0; t < 2; ++t){
        const int j = wave*128 + t*64 + lane;
        float xj0 = x[(base+j)*3+0];
        float xj1 = x[(base+j)*3+1];
        float xj2 = x[(base+j)*3+2];
        float d0 = xi0-xj0, d1 = xi1-xj1, d2c = xi2-xj2;
        float d2v = d0*d0 + d1*d1 + d2c*d2c;
        bool pass = (d2v < r2) && (j != i);
        unsigned long long bal = __ballot(pass);
        int pos = __popcll(bal & ((1ull << lane) - 1ull));
        if (pass) jseg[wave][wcnt + pos] = (unsigned short)j;
        wcnt += __popcll(bal);
    }
    if (lane == 0) cnts[wave] = wcnt;
    __syncthreads();                         // S1: cnts/his/w3s ready
    const int c0n = cnts[0], c1n = cnts[1], c2n = cnts[2], c3n = cnts[3];
    const int total = c0n + c1n + c2n + c3n;
    const int off = (wave > 0 ? c0n : 0) + (wave > 1 ? c1n : 0) + (wave > 2 ? c2n : 0);
    for (int k2 = lane; k2 < wcnt; k2 += 64)
        jlist[off + k2] = jseg[wave][k2];
    __syncthreads();                         // S2: jlist ready

    const int nch = (total + JB - 1) / JB;

    float agg[4] = {0.f, 0.f, 0.f, 0.f};
    float cx = 0.f, cy = 0.f, cz = 0.f;

    // prologue: prefetch chunk 0
    short8 hjn[4];
    float xjn0 = 0.f, xjn1 = 0.f, xjn2 = 0.f, mfn = 0.f;
    if (nch > 0){
        const int idx = lane;
        const int vld = idx < total;
        const int jn = vld ? jlist[idx] : jlist[total-1];
        mfn = vld ? 1.f : 0.f;
        #pragma unroll
        for (int k = 0; k < 4; ++k)
            hjn[k] = *(const short8*)&hj_eb[(base + jn)*EHH + wave*32 + k*8];
        xjn0 = x[(base+jn)*3+0];
        xjn1 = x[(base+jn)*3+1];
        xjn2 = x[(base+jn)*3+2];
    }

    #pragma unroll 1
    for (int c = 0; c < nch; ++c){
        const int buf = c & 1;
        const int r = lane;

        // -------- phase A: geometry + A1 build (from prefetched regs) ----
        float d0 = xi0 - xjn0;
        float d1 = xi1 - xjn1;
        float d2c = xi2 - xjn2;
        float d2v = d0*d0 + d1*d1 + d2c*d2c;
        float mf = mfn;
        if (wave == 0){
            dxs[buf][r][0] = d0; dxs[buf][r][1] = d1;
            dxs[buf][r][2] = d2c; dxs[buf][r][3] = mf;
            float t = mf * bc2v;
            cx += d0*t; cy += d1*t; cz += d2c*t;
        }
        const int sw = ((r>>3)&1)<<3;
        #pragma unroll
        for (int k = 0; k < 4; ++k){
            const int c0 = wave*32 + k*8;
            short8 hj8 = hjn[k];
            f32x4 hiA = *(const f32x4*)&his[c0];
            f32x4 hiB = *(const f32x4*)&his[c0+4];
            f32x4 w3A = *(const f32x4*)&w3s[c0];
            f32x4 w3B = *(const f32x4*)&w3s[c0+4];
            float p[8];
            #pragma unroll
            for (int e = 0; e < 4; ++e){
                float hv0 = __uint_as_float(((unsigned int)(unsigned short)hj8[e]) << 16);
                float hv1 = __uint_as_float(((unsigned int)(unsigned short)hj8[e+4]) << 16);
                p[e]   = fsilu(hiA[e] + hv0 + d2v*w3A[e]);
                p[e+4] = fsilu(hiB[e] + hv1 + d2v*w3B[e]);
            }
            short8 outv;
            ((unsigned int*)&outv)[0] = cvt_pk_bf16(p[0], p[1]);
            ((unsigned int*)&outv)[1] = cvt_pk_bf16(p[2], p[3]);
            ((unsigned int*)&outv)[2] = cvt_pk_bf16(p[4], p[5]);
            ((unsigned int*)&outv)[3] = cvt_pk_bf16(p[6], p[7]);
            *(short8*)&A1[r][c0 ^ sw] = outv;
        }
        // prefetch chunk c+1 (lands during GEMM1+GEMM2)
        if (c + 1 < nch){
            const int idx = (c+1)*JB + lane;
            const int vld = idx < total;
            const int jn = vld ? jlist[idx] : jlist[total-1];
            mfn = vld ? 1.f : 0.f;
            #pragma unroll
            for (int k = 0; k < 4; ++k)
                hjn[k] = *(const short8*)&hj_eb[(base + jn)*EHH + wave*32 + k*8];
            xjn0 = x[(base+jn)*3+0];
            xjn1 = x[(base+jn)*3+1];
            xjn2 = x[(base+jn)*3+2];
        }
        __syncthreads();                      // B2: A1/dxs ready

        // -------- GEMM1: m_pre = A1 @ We2 ---------------------------------
        f32x4 acc[2][4];
        #pragma unroll
        for (int mt = 0; mt < 2; ++mt)
            #pragma unroll
            for (int nt = 0; nt < 4; ++nt) acc[mt][nt] = (f32x4){0.f,0.f,0.f,0.f};

        const int swr = ((l15>>3)&1)<<3;
        #pragma unroll
        for (int ks = 0; ks < 4; ++ks){
            short8 afr[2];
            #pragma unroll
            for (int mt = 0; mt < 2; ++mt){
                const int row = wm*32 + mt*16 + l15;
                afr[mt] = *(const short8*)&A1[row][(ks*32 + g*8) ^ swr];
            }
            #pragma unroll
            for (int nt = 0; nt < 4; ++nt)
                #pragma unroll
                for (int mt = 0; mt < 2; ++mt)
                    acc[mt][nt] = __builtin_amdgcn_mfma_f32_16x16x32_bf16(
                        afr[mt], bW1[nt][ks], acc[mt][nt], 0, 0, 0);
        }

        // -------- epi1: m = silu(acc+be2)*mask; agg += m; mA8 = m*8 -------
        #pragma unroll
        for (int mt = 0; mt < 2; ++mt){
            float mfr[4];
            #pragma unroll
            for (int rg = 0; rg < 4; ++rg)
                mfr[rg] = dxs[buf][wm*32 + mt*16 + g*4 + rg][3];
            #pragma unroll
            for (int nt = 0; nt < 4; ++nt){
                const int col = wn*64 + nt*16 + l15;
                f32x4 v = acc[mt][nt];
                #pragma unroll
                for (int rg = 0; rg < 4; ++rg){
                    const int row = wm*32 + mt*16 + g*4 + rg;
                    float m = fsilu(v[rg] + be2r[nt]) * mfr[rg];
                    agg[nt] += m;
                    mA8[row][col] = (unsigned char)(cvt_pk_fp8(m * 8.f, 0.f) & 0xffu);
                }
            }
        }
        __syncthreads();                      // B3: mA8 ready

        // -------- GEMM2 (fp8): g1_pre = m @ Wc1 ---------------------------
        f32x4 acc2[2][4];
        #pragma unroll
        for (int mt = 0; mt < 2; ++mt)
            #pragma unroll
            for (int nt = 0; nt < 4; ++nt) acc2[mt][nt] = (f32x4){0.f,0.f,0.f,0.f};

        #pragma unroll
        for (int ks = 0; ks < 4; ++ks){
            long a8[2];
            #pragma unroll
            for (int mt = 0; mt < 2; ++mt){
                const int row = wm*32 + mt*16 + l15;
                a8[mt] = *(const long*)&mA8[row][ks*32 + g*8];
            }
            #pragma unroll
            for (int nt = 0; nt < 4; ++nt)
                #pragma unroll
                for (int mt = 0; mt < 2; ++mt)
                    acc2[mt][nt] = __builtin_amdgcn_mfma_f32_16x16x32_fp8_fp8(
                        a8[mt], bW2[nt][ks], acc2[mt][nt], 0, 0, 0);
        }

        // -------- epi2: gate partials + per-lane coord accumulation -------
        float gp[2][4];
        #pragma unroll
        for (int mt = 0; mt < 2; ++mt)
            #pragma unroll
            for (int rg = 0; rg < 4; ++rg) gp[mt][rg] = 0.f;
        #pragma unroll
        for (int mt = 0; mt < 2; ++mt)
            #pragma unroll
            for (int nt = 0; nt < 4; ++nt){
                f32x4 v = acc2[mt][nt];
                #pragma unroll
                for (int rg = 0; rg < 4; ++rg)
                    gp[mt][rg] += fsilu(v[rg]*(1.f/128.f) + bc1r[nt]) * wc2r[nt];
            }
        #pragma unroll
        for (int mt = 0; mt < 2; ++mt)
            #pragma unroll
            for (int rg = 0; rg < 4; ++rg){
                const int row = wm*32 + mt*16 + g*4 + rg;
                f32x4 dv = *(const f32x4*)&dxs[buf][row][0];
                float gv = gp[mt][rg] * dv[3];
                cx += dv[0]*gv; cy += dv[1]*gv; cz += dv[2]*gv;
            }
        // no barrier: next phase A writes A1 (reads done pre-B3) and dxs[buf^1]
    }

    // -------- agg write ----------------------------------------------------
    #pragma unroll
    for (int nt = 0; nt < 4; ++nt){
        float t = agg[nt];
        t += __shfl_xor(t, 16); t += __shfl_xor(t, 32);
        agg[nt] = t;
    }
    if (lane < 16){
        #pragma unroll
        for (int nt = 0; nt < 4; ++nt)
            aggp[wm][wn*64 + nt*16 + l15] = agg[nt];
    }

    // -------- coord cross-wave reduce -------------------------------------
    #pragma unroll
    for (int m = 1; m <= 32; m <<= 1){
        cx += __shfl_xor(cx, m);
        cy += __shfl_xor(cy, m);
        cz += __shfl_xor(cz, m);
    }
    if (lane == 0){
        cred[wave][0] = cx; cred[wave][1] = cy; cred[wave][2] = cz;
    }
    __syncthreads();
    if (tid < HH) aggb[(base + i)*HH + tid] = aggp[0][tid] + aggp[1][tid];
    if (tid == 0){
        float sx = cred[0][0] + cred[1][0] + cred[2][0] + cred[3][0];
        float sy = cred[0][1] + cred[1][1] + cred[2][1] + cred[3][1];
        float sz = cred[0][2] + cred[1][2] + cred[2][2] + cred[3][2];
        float inv = 1.0f / (float)(total > 0 ? total : 1);
        xout[(base+i)*3 + 0] = xi0 + sx*inv;
        xout[(base+i)*3 + 1] = xi1 + sy*inv;
        xout[(base+i)*3 + 2] = xi2 + sz*inv;
    }
}

// ---------------- node MLP: h_new = h + MLP(concat(h, agg)) ---------------
__global__ __launch_bounds__(128) void k_node(
    const float* __restrict__ h, const float* __restrict__ aggb,
    const float* __restrict__ Wn1, const float* __restrict__ bn1,
    const float* __restrict__ Wn2, const float* __restrict__ bn2,
    float* __restrict__ hout)
{
    __shared__ float hcat[8][260];
    __shared__ float t1[8][132];
    const int tid = threadIdx.x;
    const int row0 = blockIdx.x * 8;
    #pragma unroll
    for (int r = 0; r < 8; ++r){
        hcat[r][tid]      = h[(row0 + r)*HH + tid];
        hcat[r][HH + tid] = aggb[(row0 + r)*HH + tid];
    }
    __syncthreads();
    float acc[8] = {0.f,0.f,0.f,0.f,0.f,0.f,0.f,0.f};
    #pragma unroll 4
    for (int k = 0; k < 2*HH; ++k){
        float w = Wn1[k*EHH + tid];
        #pragma unroll
        for (int r = 0; r < 8; ++r) acc[r] += hcat[r][k] * w;
    }
    const float bn1v = bn1[tid];
    #pragma unroll
    for (int r = 0; r < 8; ++r) t1[r][tid] = fsilu(acc[r] + bn1v);
    __syncthreads();
    float acc2[8] = {0.f,0.f,0.f,0.f,0.f,0.f,0.f,0.f};
    #pragma unroll 4
    for (int e = 0; e < EHH; ++e){
        float w = Wn2[e*HH + tid];
        #pragma unroll
        for (int r = 0; r < 8; ++r) acc2[r] += t1[r][e] * w;
    }
    const float bn2v = bn2[tid];
    #pragma unroll
    for (int r = 0; r < 8; ++r)
        hout[(row0 + r)*HH + tid] = hcat[r][tid] + acc2[r] + bn2v;
}

extern "C" void kernel_launch(void* const* d_in, const int* in_sizes, int n_in,
                              void* d_out, int out_size, void* d_ws, size_t ws_size,
                              hipStream_t stream) {
    const float* h   = (const float*)d_in[0];
    const float* x   = (const float*)d_in[1];
    const float* We1 = (const float*)d_in[2];
    const float* be1 = (const float*)d_in[3];
    const float* We2 = (const float*)d_in[4];
    const float* be2 = (const float*)d_in[5];
    const float* Wc1 = (const float*)d_in[6];
    const float* bc1 = (const float*)d_in[7];
    const float* Wc2 = (const float*)d_in[8];
    const float* bc2 = (const float*)d_in[9];
    const float* Wn1 = (const float*)d_in[10];
    const float* bn1 = (const float*)d_in[11];
    const float* Wn2 = (const float*)d_in[12];
    const float* bn2 = (const float*)d_in[13];
    const int* radius = (const int*)d_in[14];

    float* out_h = (float*)d_out;
    float* out_x = out_h + BB*NN*HH;

    char* ws = (char*)d_ws;
    float*          hi_e  = (float*)ws;                              // 1 MB
    unsigned short* hj_eb = (unsigned short*)(ws + (1u<<20));        // 512 KB
    unsigned short* We2T  = (unsigned short*)(ws + (1u<<20) + (512u<<10));   // 32 KB
    unsigned char*  Wc1F8 = (unsigned char*)(ws + (1u<<20) + (544u<<10));    // 16 KB
    float*          aggb  = (float*)(ws + (1u<<20) + (560u<<10));    // 1 MB

    k_prep<<<BB*NN/8 + 16, 256, 0, stream>>>(h, We1, be1, We2, Wc1,
                                             hi_e, hj_eb, We2T, Wc1F8);
    k_edge<<<BB*NN, 256, 0, stream>>>(x, hi_e, hj_eb, We2T, Wc1F8,
                                      We1, be2, bc1, Wc2, bc2, radius,
                                      aggb, out_x);
    k_node<<<BB*NN/8, 128, 0, stream>>>(h, aggb, Wn1, bn1, Wn2, bn2, out_h);
}